// Round 10
// baseline (249.917 us; speedup 1.0000x reference)
//
#include <hip/hip_runtime.h>
#include <hip/hip_bf16.h>

// Problem constants
#define NB   4
#define SEQ  2048
#define DMODEL 1024
#define NHEAD 16
#define HDIM 64
#define MROWS (NB * SEQ)          // 8192
#define N_QKV (3 * DMODEL)        // 3072

typedef __attribute__((ext_vector_type(8))) short bf16x8;
typedef __attribute__((ext_vector_type(4))) float f32x4;
typedef __attribute__((ext_vector_type(2))) unsigned int u32x2;

#define MFMA16(a, b, c) __builtin_amdgcn_mfma_f32_16x16x32_bf16((a), (b), (c), 0, 0, 0)

// single 16B load (global: global_load_dwordx4; LDS: ds_read_b128)
__device__ inline bf16x8 load16(const __hip_bfloat16* p) {
    union { uint4 u; bf16x8 v; } t;
    t.u = *(const uint4*)p;
    return t.v;
}

// fp32 -> bf16 raw bits, round-to-nearest-even
__device__ inline ushort f2bf(float f) {
    union { float f; unsigned int u; } a;
    a.f = f;
    unsigned int r = a.u + 0x7FFFu + ((a.u >> 16) & 1u);
    return (ushort)(r >> 16);
}

// HW pack: 2 f32 -> 2 bf16 in one u32 (lo -> low half). No builtin on gfx950.
__device__ inline unsigned int cvt_pk_bf16(float lo, float hi) {
    unsigned int r;
    asm("v_cvt_pk_bf16_f32 %0, %1, %2" : "=v"(r) : "v"(lo), "v"(hi));
    return r;
}

// async global->LDS, 16B per lane; dest is WAVE-UNIFORM base (+ lane*16 by HW)
__device__ inline void gload_lds16(const __hip_bfloat16* g, __hip_bfloat16* l) {
    __builtin_amdgcn_global_load_lds(
        (const __attribute__((address_space(1))) unsigned int*)g,
        (__attribute__((address_space(3))) unsigned int*)l,
        16, 0, 0);
}

// ---------------- fused cast fp32 -> bf16 for x | w_attn | w_proj ----------------
__global__ __launch_bounds__(256)
void cast3_kernel(const float* __restrict__ x, const float* __restrict__ wa,
                  const float* __restrict__ wp, ushort* __restrict__ xb,
                  ushort* __restrict__ wab, ushort* __restrict__ wpb, float qsc) {
    const int bid = (int)blockIdx.x;
    const float* in; ushort* out; int idx; float s = 1.0f;
    if (bid < 8192) {                       // x: 8192*1024 elems
        in = x;  out = xb;  idx = (bid * 256 + (int)threadIdx.x) * 4;
    } else if (bid < 11264) {               // w_attn: 3072*1024
        in = wa; out = wab; idx = ((bid - 8192) * 256 + (int)threadIdx.x) * 4;
        if (idx < DMODEL * DMODEL) s = qsc; // W_q rows pre-scaled
    } else {                                // w_proj: 1024*1024
        in = wp; out = wpb; idx = ((bid - 11264) * 256 + (int)threadIdx.x) * 4;
    }
    float4 v = *(const float4*)(in + idx);
    ushort4 o;
    o.x = f2bf(v.x * s);
    o.y = f2bf(v.y * s);
    o.z = f2bf(v.z * s);
    o.w = f2bf(v.w * s);
    *(ushort4*)(out + idx) = o;
}

// ---------------- C[M,N] = A[M,K] * B[N,K]^T  (bf16 in, f32 acc) ----------------
// m201-GEOMETRY 4-PHASE PIPELINE: BM=BN=256, BK=64, 8 waves (2M x 4N) each
// owning 128x64 (acc[8][4], 64 MFMA/K-tile). 2 LDS buffers (128KB, 1 blk/CU).
// Per K-tile: 4 phases of 16 MFMA. B-frags (8 b128) read ONCE at ph0 and held
// in regs across all phases; A-pair (4 b128) read per phase -> LDS-read bytes
// 0.375 KB/MFMA (vs 0.5 in the 2-phase R9 kernel) + staging 0.125.
// STAGING LEDGER (derived; 2 calls/phase, FIFO vmcnt retirement):
//   tile t issues: ph0: A1,A3(t+1)->buf^1 | ph1: B0,B1(t+2)->buf |
//                  ph2: B2,B3(t+2)->buf   | ph3: A0,A2(t+2)->buf
//   every write lands in a region whose reads finished >=1 phase earlier
//   (B(t) consumed into regs at ph0; A0/A2(t) read ph0-1; A1/A3(t) read ph2-3).
//   waits: vmcnt(10)@ph1 retires A1A3(t) before ph2 reads; vmcnt(8)@ph3
//   retires B+A0A2(t+1) before next tile's ph0. vmcnt(0) only in last 2 tiles.
// T5 setprio around each 16-MFMA cluster; T1 XCD swizzle; XOR-8 LDS swizzle
// via pre-swizzled global source (rule 21).
// MODE 1: f32 plain output (N==DMODEL).
// MODE 2: QKV -- regions: Q[8192x1024] | K[8192x1024] | V^T[64bh][64d][2048s].
template<int MODE>
__global__ __launch_bounds__(512, 2)
void gemm_bt(const __hip_bfloat16* __restrict__ A,
             const __hip_bfloat16* __restrict__ Bm,
             ushort* __restrict__ Cb,
             float* __restrict__ Cf,
             ushort* __restrict__ Vt,
             int M, int N, int K) {
    constexpr int BM = 256, BN = 256, BK = 64;
    __shared__ __hip_bfloat16 As[2 * BM * BK];   // 2 x 32KB
    __shared__ __hip_bfloat16 Bs[2 * BN * BK];   // 2 x 32KB

    const int tid  = threadIdx.x;       // 512
    const int wave = tid >> 6;          // 0..7
    const int lane = tid & 63;
    const int quad = lane >> 4;
    const int l16  = lane & 15;
    const int wr = (wave >> 2) * 128;   // 0,128        (M within tile)
    const int wc = (wave & 3) * 64;     // 0,64,128,192 (N within tile)
    const int sw8 = l16 & 7;            // read-side slot XOR (row & 7)

    // XCD-aware block swizzle (nblk % 8 == 0 for both modes)
    const int nbx  = gridDim.x;
    const int nblk = nbx * gridDim.y;
    const int orig = (int)blockIdx.y * nbx + (int)blockIdx.x;
    const int swzb = (orig & 7) * (nblk >> 3) + (orig >> 3);
    const int bx = swzb % nbx, by = swzb / nbx;

    const int row0 = by * BM;
    const int col0 = bx * BN;

    // ---- staging: thread t covers row (t>>3) of a 64-row call, 16B slot (t&7);
    // source slot pre-swizzled: (t&7) ^ ((t>>3)&7)  (row&7 invariant across calls)
    const int srow = tid >> 3;                       // 0..63
    const int ssl  = ((tid & 7) ^ ((tid >> 3) & 7)) * 8;
    const __hip_bfloat16* ag = A  + (size_t)(row0 + srow) * K + ssl;
    const __hip_bfloat16* bg = Bm + (size_t)(col0 + srow) * K + ssl;

    // one call = 512 thr x 16B = 8KB = 64 rows x 128B (linear LDS dest)
    auto stageA = [&](int q, int tile, int buf) {    // q=0..3: A rows q*64..+63
        gload_lds16(ag + (size_t)tile * BK + (size_t)(q * 64) * K,
                    As + buf * 16384 + q * 4096 + wave * 512);
    };
    auto stageB = [&](int q, int tile, int buf) {    // q=0..3: B rows q*64..+63
        gload_lds16(bg + (size_t)tile * BK + (size_t)(q * 64) * K,
                    Bs + buf * 16384 + q * 4096 + wave * 512);
    };

    f32x4 acc[8][4];
#pragma unroll
    for (int i = 0; i < 8; i++)
#pragma unroll
        for (int j = 0; j < 4; j++) acc[i][j] = (f32x4)0.0f;

    // prologue: tile0 full (8 calls), tile1: B all + A0,A2 (6 calls).
    // vmcnt(6) -> tile0 fully retired (tile1's 6 newest may stay in flight).
#pragma unroll
    for (int q = 0; q < 4; q++) stageB(q, 0, 0);
    stageA(0, 0, 0); stageA(2, 0, 0); stageA(1, 0, 0); stageA(3, 0, 0);
#pragma unroll
    for (int q = 0; q < 4; q++) stageB(q, 1, 1);
    stageA(0, 1, 1); stageA(2, 1, 1);
    asm volatile("s_waitcnt vmcnt(6)" ::: "memory");
    __builtin_amdgcn_s_barrier();
    asm volatile("" ::: "memory");

    const int nk = K / BK;                           // 16
    for (int t = 0; t < nk; ++t) {
        const int cur = t & 1;
        const int nxt = cur ^ 1;
        const __hip_bfloat16* Ab = As + cur * 16384;
        const __hip_bfloat16* Bb = Bs + cur * 16384;
        const bool p1 = (t + 1 < nk), p2 = (t + 2 < nk);

        bf16x8 bfr[4][2], af[2][2];

        // ---------- phase 0: all B (8) + A m0,m1 (4); stage A1,A3(t+1) ----------
#pragma unroll
        for (int j = 0; j < 4; j++)
#pragma unroll
            for (int ks = 0; ks < 2; ks++)
                bfr[j][ks] = load16(&Bb[(wc + j * 16 + l16) * 64
                                        + (((ks * 4 + quad) ^ sw8) * 8)]);
#pragma unroll
        for (int i2 = 0; i2 < 2; i2++)
#pragma unroll
            for (int ks = 0; ks < 2; ks++)
                af[i2][ks] = load16(&Ab[(wr + i2 * 16 + l16) * 64
                                        + (((ks * 4 + quad) ^ sw8) * 8)]);
        if (p1) { stageA(1, t + 1, nxt); stageA(3, t + 1, nxt); }
        __builtin_amdgcn_s_barrier();
        asm volatile("" ::: "memory");
        __builtin_amdgcn_s_setprio(1);
#pragma unroll
        for (int i2 = 0; i2 < 2; i2++)
#pragma unroll
            for (int j = 0; j < 4; j++) {
                acc[i2][j] = MFMA16(af[i2][0], bfr[j][0], acc[i2][j]);
                acc[i2][j] = MFMA16(af[i2][1], bfr[j][1], acc[i2][j]);
            }
        __builtin_amdgcn_s_setprio(0);
        __builtin_amdgcn_s_barrier();
        asm volatile("" ::: "memory");

        // ---------- phase 1: A m2,m3; stage B0,B1(t+2); vmcnt ----------
#pragma unroll
        for (int i2 = 0; i2 < 2; i2++)
#pragma unroll
            for (int ks = 0; ks < 2; ks++)
                af[i2][ks] = load16(&Ab[(wr + 32 + i2 * 16 + l16) * 64
                                        + (((ks * 4 + quad) ^ sw8) * 8)]);
        if (p2) { stageB(0, t + 2, cur); stageB(1, t + 2, cur); }
        if (p2) asm volatile("s_waitcnt vmcnt(10)" ::: "memory");
        else    asm volatile("s_waitcnt vmcnt(0)"  ::: "memory");
        __builtin_amdgcn_s_barrier();
        asm volatile("" ::: "memory");
        __builtin_amdgcn_s_setprio(1);
#pragma unroll
        for (int i2 = 0; i2 < 2; i2++)
#pragma unroll
            for (int j = 0; j < 4; j++) {
                acc[2 + i2][j] = MFMA16(af[i2][0], bfr[j][0], acc[2 + i2][j]);
                acc[2 + i2][j] = MFMA16(af[i2][1], bfr[j][1], acc[2 + i2][j]);
            }
        __builtin_amdgcn_s_setprio(0);
        __builtin_amdgcn_s_barrier();
        asm volatile("" ::: "memory");

        // ---------- phase 2: A m4,m5; stage B2,B3(t+2) ----------
#pragma unroll
        for (int i2 = 0; i2 < 2; i2++)
#pragma unroll
            for (int ks = 0; ks < 2; ks++)
                af[i2][ks] = load16(&Ab[(wr + 64 + i2 * 16 + l16) * 64
                                        + (((ks * 4 + quad) ^ sw8) * 8)]);
        if (p2) { stageB(2, t + 2, cur); stageB(3, t + 2, cur); }
        __builtin_amdgcn_s_barrier();
        asm volatile("" ::: "memory");
        __builtin_amdgcn_s_setprio(1);
#pragma unroll
        for (int i2 = 0; i2 < 2; i2++)
#pragma unroll
            for (int j = 0; j < 4; j++) {
                acc[4 + i2][j] = MFMA16(af[i2][0], bfr[j][0], acc[4 + i2][j]);
                acc[4 + i2][j] = MFMA16(af[i2][1], bfr[j][1], acc[4 + i2][j]);
            }
        __builtin_amdgcn_s_setprio(0);
        __builtin_amdgcn_s_barrier();
        asm volatile("" ::: "memory");

        // ---------- phase 3: A m6,m7; stage A0,A2(t+2); vmcnt ----------
#pragma unroll
        for (int i2 = 0; i2 < 2; i2++)
#pragma unroll
            for (int ks = 0; ks < 2; ks++)
                af[i2][ks] = load16(&Ab[(wr + 96 + i2 * 16 + l16) * 64
                                        + (((ks * 4 + quad) ^ sw8) * 8)]);
        if (p2) { stageA(0, t + 2, cur); stageA(2, t + 2, cur); }
        if (p2) asm volatile("s_waitcnt vmcnt(8)" ::: "memory");
        else    asm volatile("s_waitcnt vmcnt(0)" ::: "memory");
        __builtin_amdgcn_s_barrier();
        asm volatile("" ::: "memory");
        __builtin_amdgcn_s_setprio(1);
#pragma unroll
        for (int i2 = 0; i2 < 2; i2++)
#pragma unroll
            for (int j = 0; j < 4; j++) {
                acc[6 + i2][j] = MFMA16(af[i2][0], bfr[j][0], acc[6 + i2][j]);
                acc[6 + i2][j] = MFMA16(af[i2][1], bfr[j][1], acc[6 + i2][j]);
            }
        __builtin_amdgcn_s_setprio(0);
        __builtin_amdgcn_s_barrier();
        asm volatile("" ::: "memory");
    }
    // drain before reusing LDS as epilogue scratch
    asm volatile("s_waitcnt vmcnt(0)" ::: "memory");
    __builtin_amdgcn_s_barrier();
    asm volatile("" ::: "memory");

    if constexpr (MODE == 2) {
        if (col0 >= 2 * DMODEL) {
            // V block: 256 cols = 4 heads; wave owns 128 s x 64 d of head
            // hh = (vcol0>>6) + (wave&3). 4 passes of 32s x 64d via private LDS.
            const int vcol0 = col0 - 2 * DMODEL;
            const int bb = row0 >> 11;          // batch
            const int row0m = row0 & 2047;      // s offset within batch
            const int hh = (vcol0 >> 6) + (wave & 3);
            ushort* Tw = (ushort*)As + wave * 2048;   // [64 d][32 s] per pass
            ushort* vdst = Vt + ((size_t)(bb * NHEAD + hh) * HDIM) * SEQ;
#pragma unroll
            for (int P = 0; P < 4; P++) {
#pragma unroll
                for (int i2 = 0; i2 < 2; i2++)
#pragma unroll
                    for (int j = 0; j < 4; j++)
#pragma unroll
                        for (int r = 0; r < 4; r++)
                            Tw[(j * 16 + l16) * 32 + i2 * 16 + quad * 4 + r] =
                                f2bf(acc[2 * P + i2][j][r]);
#pragma unroll
                for (int pp = 0; pp < 4; pp++) {
                    int d = pp * 16 + (lane >> 2);
                    int part = lane & 3;
                    uint4 v = *(const uint4*)(Tw + d * 32 + part * 8);
                    *(uint4*)(vdst + (size_t)d * SEQ + row0m + wr + P * 32 + part * 8) = v;
                }
            }
            return;
        }
    }

    ushort* base = nullptr;
    int c0 = 0;
    if constexpr (MODE == 2) {
        base = Cb + ((col0 >= DMODEL) ? (size_t)MROWS * DMODEL : 0);
        c0 = col0 & (DMODEL - 1);
    }
#pragma unroll
    for (int i = 0; i < 8; i++) {
#pragma unroll
        for (int r = 0; r < 4; r++) {
            size_t grow = (size_t)(row0 + wr + i * 16 + quad * 4 + r);
#pragma unroll
            for (int j = 0; j < 4; j++) {
                float v = acc[i][j][r];
                if (MODE == 1) {
                    Cf[grow * N + col0 + wc + j * 16 + l16] = v;
                } else {
                    base[grow * DMODEL + c0 + wc + j * 16 + l16] = f2bf(v);
                }
            }
        }
    }
}

// ---------------- flash attention, causal, 4-BUFFER UNROLL-4, IN-REGISTER P ----------------
// (unchanged from R7 -- verified) Block = 4 pair-waves of the SAME (b,h),
// consecutive p in {4g..4g+3}. 4 staging buffers, inner loop unrolled x4,
// compile-time buffer index. Depth-2 counted vmcnt(2) + raw s_barrier.
// K/V source-pre-swizzled; T12 in-register P via permlane chains; fzero C-op.
__global__ __launch_bounds__(256)
void attn_kernel(const ushort* __restrict__ Qb, const ushort* __restrict__ Kb,
                 const ushort* __restrict__ Vtb, ushort* __restrict__ O) {
    __shared__ __hip_bfloat16 Kc[4 * 32 * 64];    // [buf][key][d]   4 x 4KB
    __shared__ __hip_bfloat16 Vc[4 * 64 * 32];    // [buf][d][key]   4 x 4KB

    const int tid  = threadIdx.x;
    const int wave = tid >> 6;
    const int lane = tid & 63;
    const int quad = lane >> 4;
    const int l16  = lane & 15;

    const int blk = (int)blockIdx.x;              // 1024 blocks
    const int g   = 15 - (blk >> 6);              // p-group, longest first (LPT)
    const int bh  = (((blk >> 3) & 7) << 3) | (blk & 7);  // bh%8 == blk%8 (XCD affinity)
    const int b = bh >> 4, h = bh & 15;
    const int p  = 4 * g + wave;                  // this wave's q-pair
    const int q0 = p * 32;
    const int nc = p + 1;                         // this wave's chunk count
    const int ncmax = 4 * g + 4;                  // block's chunk count (uniform, %4==0)

    // ones B-fragment for the l-sum MFMA (bf16 1.0 = 0x3F80)
    bf16x8 ones;
#pragma unroll
    for (int i = 0; i < 8; i++) ones[i] = (short)0x3F80;
    const f32x4 fzero = (f32x4)0.0f;              // persistent zero C-operand

    // Q fragments for both strips; Wq pre-scaled by 0.125*log2(e)
    bf16x8 qf[2][2];
#pragma unroll
    for (int s = 0; s < 2; s++) {
        const __hip_bfloat16* qp = (const __hip_bfloat16*)Qb
            + ((size_t)b * SEQ + q0 + s * 16 + l16) * DMODEL + h * HDIM;
        qf[s][0] = load16(qp + quad * 8);
        qf[s][1] = load16(qp + 32 + quad * 8);
    }

    const __hip_bfloat16* kbase = (const __hip_bfloat16*)Kb + (size_t)b * SEQ * DMODEL + h * HDIM;
    const __hip_bfloat16* vbase = (const __hip_bfloat16*)Vtb + (size_t)bh * HDIM * SEQ;

    f32x4 oacc[2][4], lacc[2];
#pragma unroll
    for (int s = 0; s < 2; s++) {
        lacc[s] = (f32x4)0.0f;
#pragma unroll
        for (int t = 0; t < 4; t++) oacc[s][t] = (f32x4)0.0f;
    }

    // --- rolling per-lane staging pointers ---
    // K quarter: slot -> key=slot>>3, dsg=(slot&7)^(key&7)      [pre-swizzle]
    // V quarter: slot -> d=slot>>2,  sg=(slot&3)^((d>>1)&3)     [pre-swizzle]
    const int slot = wave * 64 + lane;
    const int skey = slot >> 3;
    const int sdsg = (slot & 7) ^ (skey & 7);
    const int svd  = slot >> 2;
    const int svsg = (slot & 3) ^ ((svd >> 1) & 3);
    const __hip_bfloat16* kg = kbase + (size_t)skey * DMODEL + sdsg * 8;
    const __hip_bfloat16* vg = vbase + (size_t)svd * SEQ + svsg * 8;

    auto stage = [&](int buf, int chunk) {
        gload_lds16(kg + (size_t)chunk * (32 * DMODEL), Kc + buf * 2048 + wave * 512);
        gload_lds16(vg + (size_t)chunk * 32,            Vc + buf * 2048 + wave * 512);
    };

    // prologue: fill buffers 0 and 1 (ncmax >= 4 always); wait buf0 only
    stage(0, 0);
    stage(1, 1);
    asm volatile("s_waitcnt vmcnt(2)" ::: "memory");
    __builtin_amdgcn_s_barrier();
    asm volatile("" ::: "memory");

    const int vswz = (l16 >> 1) & 3;   // V read-side XOR ((d>>1)&3; t*16 is 0 mod 4)

    for (int cb = 0; cb < ncmax; cb += 4) {
#pragma unroll
        for (int u = 0; u < 4; ++u) {           // u compile-time after unroll
            const int c = cb + u;               // buffer index == u (cb % 4 == 0)
            const bool more = (c + 2 < ncmax);
            if (more) stage((u + 2) & 3, c + 2);

            if (c < nc) {
                const int k0 = c * 32;
                const bool diag = (c == nc - 1);
                const __hip_bfloat16* Kb_l = Kc + u * 2048;   // folds into ds imm
                const __hip_bfloat16* Vb_l = Vc + u * 2048;

                // K frags: [key = t*16+l16][d-seg swz]; V^T: [d = t*16+l16][key swz]
                bf16x8 kb[2][2], vb[4];
#pragma unroll
                for (int t = 0; t < 2; t++) {
#pragma unroll
                    for (int hf = 0; hf < 2; hf++)
                        kb[t][hf] = load16(&Kb_l[(t * 16 + l16) * 64
                                                 + (((hf * 4 + quad) ^ (l16 & 7)) * 8)]);
                }
#pragma unroll
                for (int t = 0; t < 4; t++)
                    vb[t] = load16(&Vb_l[(t * 16 + l16) * 32 + ((quad ^ vswz) * 8)]);

                // per strip: S^T -> exp2 -> cvt_pk -> permlane redistribute -> PV
#pragma unroll
                for (int s = 0; s < 2; s++) {
                    // z[t][r] = S[key = k0 + t*16 + quad*4 + r, q = q0 + s*16 + l16]
                    f32x4 z[2];
#pragma unroll
                    for (int t = 0; t < 2; t++) {
                        f32x4 zz = MFMA16(kb[t][0], qf[s][0], fzero);
                        zz = MFMA16(kb[t][1], qf[s][1], zz);
                        z[t] = zz;
                    }

                    unsigned int xw0, xw1, yw0, yw1;
#pragma unroll
                    for (int t = 0; t < 2; t++) {
                        float e[4];
#pragma unroll
                        for (int r = 0; r < 4; r++) {
                            float sv = z[t][r];
                            if (diag) {
                                int key = k0 + t * 16 + quad * 4 + r;
                                int qq  = q0 + s * 16 + l16;
                                sv = (key <= qq) ? sv : -1e30f;
                            }
                            e[r] = __builtin_amdgcn_exp2f(sv);   // raw v_exp_f32
                        }
                        unsigned int w0 = cvt_pk_bf16(e[0], e[1]);
                        unsigned int w1 = cvt_pk_bf16(e[2], e[3]);
                        if (t == 0) { xw0 = w0; xw1 = w1; }
                        else        { yw0 = w0; yw1 = w1; }
                    }

                    // in-register P -> A-frag redistribution (T12), no LDS round-trip
                    u32x2 s32_0 = __builtin_amdgcn_permlane32_swap(xw0, yw0, false, false);
                    u32x2 fin_0 = __builtin_amdgcn_permlane16_swap(s32_0.x, s32_0.y, false, false);
                    u32x2 s32_1 = __builtin_amdgcn_permlane32_swap(xw1, yw1, false, false);
                    u32x2 fin_1 = __builtin_amdgcn_permlane16_swap(s32_1.x, s32_1.y, false, false);
                    union { unsigned int u[4]; bf16x8 v; } pk;
                    pk.u[0] = fin_0.x; pk.u[1] = fin_1.x;
                    pk.u[2] = fin_0.y; pk.u[3] = fin_1.y;
                    bf16x8 pa = pk.v;

#pragma unroll
                    for (int t = 0; t < 4; t++)
                        oacc[s][t] = MFMA16(pa, vb[t], oacc[s][t]);
                    lacc[s] = MFMA16(pa, ones, lacc[s]);  // row-sum via matrix pipe
                }
            }

            // counted drain: c+1's loads done; c+2's (if issued) may stay in flight
            if (more) asm volatile("s_waitcnt vmcnt(2)" ::: "memory");
            else      asm volatile("s_waitcnt vmcnt(0)" ::: "memory");
            __builtin_amdgcn_s_barrier();
            asm volatile("" ::: "memory");
        }
    }

    // normalize + store O as bf16 [B*S, D] at head offset
#pragma unroll
    for (int s = 0; s < 2; s++) {
        float inv[4];
#pragma unroll
        for (int r = 0; r < 4; r++) inv[r] = 1.0f / lacc[s][r];
#pragma unroll
        for (int t = 0; t < 4; t++) {
#pragma unroll
            for (int r = 0; r < 4; r++) {
                float v = oacc[s][t][r] * inv[r];
                O[((size_t)b * SEQ + q0 + s * 16 + quad * 4 + r) * DMODEL
                  + h * HDIM + t * 16 + l16] = f2bf(v);
            }
        }
    }
}

extern "C" void kernel_launch(void* const* d_in, const int* in_sizes, int n_in,
                              void* d_out, int out_size, void* d_ws, size_t ws_size,
                              hipStream_t stream) {
    const float* x      = (const float*)d_in[0];
    const float* w_attn = (const float*)d_in[1];
    const float* w_proj = (const float*)d_in[2];
    float* out = (float*)d_out;

    // workspace (bf16 elems): x | w_attn | w_proj | qkv{Q|K|V^T} | o
    ushort* ws   = (ushort*)d_ws;
    ushort* xb   = ws;
    ushort* wab  = xb  + (size_t)MROWS * DMODEL;
    ushort* wpb  = wab + (size_t)N_QKV * DMODEL;
    ushort* qkvb = wpb + (size_t)DMODEL * DMODEL;
    ushort* ob   = qkvb + (size_t)MROWS * N_QKV;

    ushort* qreg = qkvb;
    ushort* kreg = qkvb + (size_t)MROWS * DMODEL;
    ushort* vtreg = qkvb + 2 * (size_t)MROWS * DMODEL;

    const float qsc = 0.125f * 1.44269504f;  // softmax scale * log2(e) folded into W_q

    // fused casts: x (8192 blk) | w_attn (3072 blk) | w_proj (1024 blk)
    cast3_kernel<<<12288, 256, 0, stream>>>(x, w_attn, w_proj, xb, wab, wpb, qsc);

    // qkv = x @ w_attn^T -> Q | K | V^T regions  (256x256 tiles, 512 thr, 4-phase)
    gemm_bt<2><<<dim3(N_QKV / 256, MROWS / 256), 512, 0, stream>>>(
        (const __hip_bfloat16*)xb, (const __hip_bfloat16*)wab, qreg, nullptr, vtreg,
        MROWS, N_QKV, DMODEL);

    // flash attention -> o (4 pair-waves/block, 4-buffer unroll-4, in-register P)
    attn_kernel<<<1024, 256, 0, stream>>>(qreg, kreg, vtreg, ob);

    // out = o @ w_proj^T   [8192,1024] f32
    gemm_bt<1><<<dim3(DMODEL / 256, MROWS / 256), 512, 0, stream>>>(
        (const __hip_bfloat16*)ob, (const __hip_bfloat16*)wpb, nullptr, out, nullptr,
        MROWS, DMODEL, DMODEL);
}

// Round 11
// 231.431 us; speedup vs baseline: 1.0799x; 1.0799x over previous
//
#include <hip/hip_runtime.h>
#include <hip/hip_bf16.h>

// Problem constants
#define NB   4
#define SEQ  2048
#define DMODEL 1024
#define NHEAD 16
#define HDIM 64
#define MROWS (NB * SEQ)          // 8192
#define N_QKV (3 * DMODEL)        // 3072

typedef __attribute__((ext_vector_type(8))) short bf16x8;
typedef __attribute__((ext_vector_type(4))) float f32x4;
typedef __attribute__((ext_vector_type(2))) unsigned int u32x2;

#define MFMA16(a, b, c) __builtin_amdgcn_mfma_f32_16x16x32_bf16((a), (b), (c), 0, 0, 0)

// single 16B load (global: global_load_dwordx4; LDS: ds_read_b128)
__device__ inline bf16x8 load16(const __hip_bfloat16* p) {
    union { uint4 u; bf16x8 v; } t;
    t.u = *(const uint4*)p;
    return t.v;
}

// fp32 -> bf16 raw bits, round-to-nearest-even
__device__ inline ushort f2bf(float f) {
    union { float f; unsigned int u; } a;
    a.f = f;
    unsigned int r = a.u + 0x7FFFu + ((a.u >> 16) & 1u);
    return (ushort)(r >> 16);
}

// HW pack: 2 f32 -> 2 bf16 in one u32 (lo -> low half). No builtin on gfx950.
__device__ inline unsigned int cvt_pk_bf16(float lo, float hi) {
    unsigned int r;
    asm("v_cvt_pk_bf16_f32 %0, %1, %2" : "=v"(r) : "v"(lo), "v"(hi));
    return r;
}

// async global->LDS, 16B per lane; dest is WAVE-UNIFORM base (+ lane*16 by HW)
__device__ inline void gload_lds16(const __hip_bfloat16* g, __hip_bfloat16* l) {
    __builtin_amdgcn_global_load_lds(
        (const __attribute__((address_space(1))) unsigned int*)g,
        (__attribute__((address_space(3))) unsigned int*)l,
        16, 0, 0);
}

// ---------------- fused cast fp32 -> bf16 for x | w_attn | w_proj ----------------
__global__ __launch_bounds__(256)
void cast3_kernel(const float* __restrict__ x, const float* __restrict__ wa,
                  const float* __restrict__ wp, ushort* __restrict__ xb,
                  ushort* __restrict__ wab, ushort* __restrict__ wpb, float qsc) {
    const int bid = (int)blockIdx.x;
    const float* in; ushort* out; int idx; float s = 1.0f;
    if (bid < 8192) {                       // x: 8192*1024 elems
        in = x;  out = xb;  idx = (bid * 256 + (int)threadIdx.x) * 4;
    } else if (bid < 11264) {               // w_attn: 3072*1024
        in = wa; out = wab; idx = ((bid - 8192) * 256 + (int)threadIdx.x) * 4;
        if (idx < DMODEL * DMODEL) s = qsc; // W_q rows pre-scaled
    } else {                                // w_proj: 1024*1024
        in = wp; out = wpb; idx = ((bid - 11264) * 256 + (int)threadIdx.x) * 4;
    }
    float4 v = *(const float4*)(in + idx);
    ushort4 o;
    o.x = f2bf(v.x * s);
    o.y = f2bf(v.y * s);
    o.z = f2bf(v.z * s);
    o.w = f2bf(v.w * s);
    *(ushort4*)(out + idx) = o;
}

// ---------------- C[M,N] = A[M,K] * B[N,K]^T  (bf16 in, f32 acc) ----------------
// PHASE-INTERLEAVED PIPELINE (R9-verified structure, best-known config):
// BM=256 x BN=128, BK=64, 8 waves (4M x 2N) each owning 64x64 (acc[4][4]).
// 3 LDS buffers (144KB, 1 block/CU). K-tile = 2 phases of 16 MFMA:
//   phase: { ds_read frag subtile -> issue 3 staging loads (tile t+2) ->
//            s_barrier -> setprio(1) -> 16 MFMA -> setprio(0) -> s_barrier }
// vmcnt(6) ONCE per K-tile (t+2's 6 loads stay in flight; t+1 guaranteed
// landed) -- never 0 in the loop. XOR-8 LDS swizzle via pre-swizzled global
// source (rule 21) -> conflict-free ds_read_b128.
// NEW (R11): XCD 2-D RECTANGLE BLOCKING -- blocks i with i%8==xcd form
// 4-row x 8-col rects of 32 blocks; per-rect working set = 4 A-panels (2MB)
// + 8 B-panels (2MB) = 4MB = one XCD's L2. A reused 8x, B 4x from L2.
// Bijective for nbx%8==0 (24/8) and nby%4==0 (32).
// MODE 1: f32 plain output (N==DMODEL).
// MODE 2: QKV -- regions: Q[8192x1024] | K[8192x1024] | V^T[64bh][64d][2048s].
template<int MODE>
__global__ __launch_bounds__(512, 2)
void gemm_bt(const __hip_bfloat16* __restrict__ A,
             const __hip_bfloat16* __restrict__ Bm,
             ushort* __restrict__ Cb,
             float* __restrict__ Cf,
             ushort* __restrict__ Vt,
             int M, int N, int K) {
    constexpr int BM = 256, BN = 128, BK = 64;
    __shared__ __hip_bfloat16 As[3 * BM * BK];   // 3 x 32KB
    __shared__ __hip_bfloat16 Bs[3 * BN * BK];   // 3 x 16KB

    const int tid  = threadIdx.x;       // 512
    const int wave = tid >> 6;          // 0..7
    const int lane = tid & 63;
    const int quad = lane >> 4;
    const int l16  = lane & 15;
    const int wr = (wave >> 1) * 64;    // 0,64,128,192  (M within tile)
    const int wc = (wave & 1) * 64;     // 0,64          (N within tile)
    const int sw8 = l16 & 7;            // read-side slot XOR (row & 7)

    // XCD 2-D rectangle blocking (replaces 1-D chunk swizzle):
    // i%8 -> XCD; k=i/8 walks that XCD's rects (32 blocks each, 4 rows x 8 cols)
    const int nbx  = gridDim.x;             // 24 (MODE2) / 8 (MODE1)
    const int nRx  = nbx >> 3;              // col-groups per row-group: 3 / 1
    const int i    = (int)blockIdx.y * nbx + (int)blockIdx.x;
    const int xcd  = i & 7;
    const int kk   = i >> 3;
    const int ridx = xcd + 8 * (kk >> 5);   // rect id
    const int pos  = kk & 31;               // position within rect
    const int rowgrp = ridx / nRx;
    const int colgrp = ridx % nRx;
    const int by = rowgrp * 4 + (pos >> 3);
    const int bx = colgrp * 8 + (pos & 7);

    const int row0 = by * BM;
    const int col0 = bx * BN;

    // ---- staging: thread t covers row (t>>3) of a 64-row chunk, 16B slot (t&7);
    // source slot pre-swizzled: (t&7) ^ ((t>>3)&7)  (row&7 invariant across chunks)
    const int srow = tid >> 3;                       // 0..63
    const int ssl  = ((tid & 7) ^ ((tid >> 3) & 7)) * 8;
    const __hip_bfloat16* ag = A  + (size_t)(row0 + srow) * K + ssl;
    const __hip_bfloat16* bg = Bm + (size_t)(col0 + srow) * K + ssl;

    // one call = 512 thr x 16B = 8KB = 64 rows x 128B (linear LDS dest)
    auto stageA = [&](int q, int tile, int buf) {    // q = 0..3 (A rows q*64..+63)
        gload_lds16(ag + (size_t)tile * BK + (size_t)(q * 64) * K,
                    As + buf * 16384 + q * 4096 + wave * 512);
    };
    auto stageB = [&](int q, int tile, int buf) {    // q = 0..1 (B rows q*64..+63)
        gload_lds16(bg + (size_t)tile * BK + (size_t)(q * 64) * K,
                    Bs + buf * 8192 + q * 4096 + wave * 512);
    };

    f32x4 acc[4][4];
#pragma unroll
    for (int i2 = 0; i2 < 4; i2++)
#pragma unroll
        for (int j = 0; j < 4; j++) acc[i2][j] = (f32x4)0.0f;

    // prologue: stage tiles 0 and 1 (6 loads each); ensure tile0 landed
#pragma unroll
    for (int q = 0; q < 4; q++) stageA(q, 0, 0);
    stageB(0, 0, 0); stageB(1, 0, 0);
#pragma unroll
    for (int q = 0; q < 4; q++) stageA(q, 1, 1);
    stageB(0, 1, 1); stageB(1, 1, 1);
    asm volatile("s_waitcnt vmcnt(6)" ::: "memory");
    __builtin_amdgcn_s_barrier();
    asm volatile("" ::: "memory");

    const int nk = K / BK;                           // 16
    int cur = 0;
    for (int t = 0; t < nk; ++t) {
        const bool more = (t + 2 < nk);
        const int nb = (cur + 2 >= 3) ? cur - 1 : cur + 2;   // (cur+2)%3
        const __hip_bfloat16* Ab = As + cur * 16384;
        const __hip_bfloat16* Bb = Bs + cur * 8192;

        // ---------- phase 0: A-half0 + all B reads; 16 MFMA (i=0,1) ----------
        bf16x8 a0[2][2], bfr[4][2];
#pragma unroll
        for (int i2 = 0; i2 < 2; i2++)
#pragma unroll
            for (int ks = 0; ks < 2; ks++)
                a0[i2][ks] = load16(&Ab[(wr + i2 * 16 + l16) * 64
                                        + (((ks * 4 + quad) ^ sw8) * 8)]);
#pragma unroll
        for (int j = 0; j < 4; j++)
#pragma unroll
            for (int ks = 0; ks < 2; ks++)
                bfr[j][ks] = load16(&Bb[(wc + j * 16 + l16) * 64
                                        + (((ks * 4 + quad) ^ sw8) * 8)]);
        if (more) { stageA(0, t + 2, nb); stageA(1, t + 2, nb); stageB(0, t + 2, nb); }

        __builtin_amdgcn_s_barrier();
        asm volatile("" ::: "memory");
        __builtin_amdgcn_s_setprio(1);
#pragma unroll
        for (int i2 = 0; i2 < 2; i2++)
#pragma unroll
            for (int j = 0; j < 4; j++) {
                acc[i2][j] = MFMA16(a0[i2][0], bfr[j][0], acc[i2][j]);
                acc[i2][j] = MFMA16(a0[i2][1], bfr[j][1], acc[i2][j]);
            }
        __builtin_amdgcn_s_setprio(0);
        __builtin_amdgcn_s_barrier();
        asm volatile("" ::: "memory");

        // ---------- phase 1: A-half1 reads; 16 MFMA (i=2,3); tile-end vmcnt ----------
        bf16x8 a1[2][2];
#pragma unroll
        for (int i2 = 0; i2 < 2; i2++)
#pragma unroll
            for (int ks = 0; ks < 2; ks++)
                a1[i2][ks] = load16(&Ab[(wr + 32 + i2 * 16 + l16) * 64
                                        + (((ks * 4 + quad) ^ sw8) * 8)]);
        if (more) { stageA(2, t + 2, nb); stageA(3, t + 2, nb); stageB(1, t + 2, nb); }

        __builtin_amdgcn_s_barrier();
        asm volatile("" ::: "memory");
        __builtin_amdgcn_s_setprio(1);
#pragma unroll
        for (int i2 = 0; i2 < 2; i2++)
#pragma unroll
            for (int j = 0; j < 4; j++) {
                acc[2 + i2][j] = MFMA16(a1[i2][0], bfr[j][0], acc[2 + i2][j]);
                acc[2 + i2][j] = MFMA16(a1[i2][1], bfr[j][1], acc[2 + i2][j]);
            }
        __builtin_amdgcn_s_setprio(0);

        // counted drain: tile t+1's 6 loads must be done; t+2's stay in flight
        if (more) asm volatile("s_waitcnt vmcnt(6)" ::: "memory");
        else      asm volatile("s_waitcnt vmcnt(0)" ::: "memory");
        __builtin_amdgcn_s_barrier();
        asm volatile("" ::: "memory");

        cur = (cur == 2) ? 0 : cur + 1;
    }
    // All staging landed, all waves past final barrier: LDS reusable as scratch.

    if constexpr (MODE == 2) {
        if (col0 >= 2 * DMODEL) {
            // V block: each wave transposes its 64s x 64d via private LDS scratch.
            const int vcol0 = col0 - 2 * DMODEL;
            const int bb = row0 >> 11;          // batch
            const int row0m = row0 & 2047;      // s offset within batch
            const int hh = (vcol0 >> 6) + (wave & 1);
            ushort* Tw = (ushort*)As + wave * 2048;   // [64 d][32 s] per pass
            ushort* vdst = Vt + ((size_t)(bb * NHEAD + hh) * HDIM) * SEQ;
#pragma unroll
            for (int P = 0; P < 2; P++) {
#pragma unroll
                for (int i2 = 0; i2 < 2; i2++)
#pragma unroll
                    for (int j = 0; j < 4; j++)
#pragma unroll
                        for (int r = 0; r < 4; r++)
                            Tw[(j * 16 + l16) * 32 + i2 * 16 + quad * 4 + r] =
                                f2bf(acc[2 * P + i2][j][r]);
#pragma unroll
                for (int pp = 0; pp < 4; pp++) {
                    int d = pp * 16 + (lane >> 2);
                    int part = lane & 3;
                    uint4 v = *(const uint4*)(Tw + d * 32 + part * 8);
                    *(uint4*)(vdst + (size_t)d * SEQ + row0m + wr + P * 32 + part * 8) = v;
                }
            }
            return;
        }
    }

    ushort* base = nullptr;
    int c0 = 0;
    if constexpr (MODE == 2) {
        base = Cb + ((col0 >= DMODEL) ? (size_t)MROWS * DMODEL : 0);
        c0 = col0 & (DMODEL - 1);
    }
#pragma unroll
    for (int i2 = 0; i2 < 4; i2++) {
#pragma unroll
        for (int r = 0; r < 4; r++) {
            size_t grow = (size_t)(row0 + wr + i2 * 16 + quad * 4 + r);
#pragma unroll
            for (int j = 0; j < 4; j++) {
                float v = acc[i2][j][r];
                if (MODE == 1) {
                    Cf[grow * N + col0 + wc + j * 16 + l16] = v;
                } else {
                    base[grow * DMODEL + c0 + wc + j * 16 + l16] = f2bf(v);
                }
            }
        }
    }
}

// ---------------- flash attention, causal, 4-BUFFER UNROLL-4, IN-REGISTER P ----------------
// (unchanged from R7 -- verified) Block = 4 pair-waves of the SAME (b,h),
// consecutive p in {4g..4g+3}. 4 staging buffers, inner loop unrolled x4,
// compile-time buffer index. Depth-2 counted vmcnt(2) + raw s_barrier.
// K/V source-pre-swizzled; T12 in-register P via permlane chains; fzero C-op.
__global__ __launch_bounds__(256)
void attn_kernel(const ushort* __restrict__ Qb, const ushort* __restrict__ Kb,
                 const ushort* __restrict__ Vtb, ushort* __restrict__ O) {
    __shared__ __hip_bfloat16 Kc[4 * 32 * 64];    // [buf][key][d]   4 x 4KB
    __shared__ __hip_bfloat16 Vc[4 * 64 * 32];    // [buf][d][key]   4 x 4KB

    const int tid  = threadIdx.x;
    const int wave = tid >> 6;
    const int lane = tid & 63;
    const int quad = lane >> 4;
    const int l16  = lane & 15;

    const int blk = (int)blockIdx.x;              // 1024 blocks
    const int g   = 15 - (blk >> 6);              // p-group, longest first (LPT)
    const int bh  = (((blk >> 3) & 7) << 3) | (blk & 7);  // bh%8 == blk%8 (XCD affinity)
    const int b = bh >> 4, h = bh & 15;
    const int p  = 4 * g + wave;                  // this wave's q-pair
    const int q0 = p * 32;
    const int nc = p + 1;                         // this wave's chunk count
    const int ncmax = 4 * g + 4;                  // block's chunk count (uniform, %4==0)

    // ones B-fragment for the l-sum MFMA (bf16 1.0 = 0x3F80)
    bf16x8 ones;
#pragma unroll
    for (int i = 0; i < 8; i++) ones[i] = (short)0x3F80;
    const f32x4 fzero = (f32x4)0.0f;              // persistent zero C-operand

    // Q fragments for both strips; Wq pre-scaled by 0.125*log2(e)
    bf16x8 qf[2][2];
#pragma unroll
    for (int s = 0; s < 2; s++) {
        const __hip_bfloat16* qp = (const __hip_bfloat16*)Qb
            + ((size_t)b * SEQ + q0 + s * 16 + l16) * DMODEL + h * HDIM;
        qf[s][0] = load16(qp + quad * 8);
        qf[s][1] = load16(qp + 32 + quad * 8);
    }

    const __hip_bfloat16* kbase = (const __hip_bfloat16*)Kb + (size_t)b * SEQ * DMODEL + h * HDIM;
    const __hip_bfloat16* vbase = (const __hip_bfloat16*)Vtb + (size_t)bh * HDIM * SEQ;

    f32x4 oacc[2][4], lacc[2];
#pragma unroll
    for (int s = 0; s < 2; s++) {
        lacc[s] = (f32x4)0.0f;
#pragma unroll
        for (int t = 0; t < 4; t++) oacc[s][t] = (f32x4)0.0f;
    }

    // --- rolling per-lane staging pointers ---
    // K quarter: slot -> key=slot>>3, dsg=(slot&7)^(key&7)      [pre-swizzle]
    // V quarter: slot -> d=slot>>2,  sg=(slot&3)^((d>>1)&3)     [pre-swizzle]
    const int slot = wave * 64 + lane;
    const int skey = slot >> 3;
    const int sdsg = (slot & 7) ^ (skey & 7);
    const int svd  = slot >> 2;
    const int svsg = (slot & 3) ^ ((svd >> 1) & 3);
    const __hip_bfloat16* kg = kbase + (size_t)skey * DMODEL + sdsg * 8;
    const __hip_bfloat16* vg = vbase + (size_t)svd * SEQ + svsg * 8;

    auto stage = [&](int buf, int chunk) {
        gload_lds16(kg + (size_t)chunk * (32 * DMODEL), Kc + buf * 2048 + wave * 512);
        gload_lds16(vg + (size_t)chunk * 32,            Vc + buf * 2048 + wave * 512);
    };

    // prologue: fill buffers 0 and 1 (ncmax >= 4 always); wait buf0 only
    stage(0, 0);
    stage(1, 1);
    asm volatile("s_waitcnt vmcnt(2)" ::: "memory");
    __builtin_amdgcn_s_barrier();
    asm volatile("" ::: "memory");

    const int vswz = (l16 >> 1) & 3;   // V read-side XOR ((d>>1)&3; t*16 is 0 mod 4)

    for (int cb = 0; cb < ncmax; cb += 4) {
#pragma unroll
        for (int u = 0; u < 4; ++u) {           // u compile-time after unroll
            const int c = cb + u;               // buffer index == u (cb % 4 == 0)
            const bool more = (c + 2 < ncmax);
            if (more) stage((u + 2) & 3, c + 2);

            if (c < nc) {
                const int k0 = c * 32;
                const bool diag = (c == nc - 1);
                const __hip_bfloat16* Kb_l = Kc + u * 2048;   // folds into ds imm
                const __hip_bfloat16* Vb_l = Vc + u * 2048;

                // K frags: [key = t*16+l16][d-seg swz]; V^T: [d = t*16+l16][key swz]
                bf16x8 kb[2][2], vb[4];
#pragma unroll
                for (int t = 0; t < 2; t++) {
#pragma unroll
                    for (int hf = 0; hf < 2; hf++)
                        kb[t][hf] = load16(&Kb_l[(t * 16 + l16) * 64
                                                 + (((hf * 4 + quad) ^ (l16 & 7)) * 8)]);
                }
#pragma unroll
                for (int t = 0; t < 4; t++)
                    vb[t] = load16(&Vb_l[(t * 16 + l16) * 32 + ((quad ^ vswz) * 8)]);

                // per strip: S^T -> exp2 -> cvt_pk -> permlane redistribute -> PV
#pragma unroll
                for (int s = 0; s < 2; s++) {
                    // z[t][r] = S[key = k0 + t*16 + quad*4 + r, q = q0 + s*16 + l16]
                    f32x4 z[2];
#pragma unroll
                    for (int t = 0; t < 2; t++) {
                        f32x4 zz = MFMA16(kb[t][0], qf[s][0], fzero);
                        zz = MFMA16(kb[t][1], qf[s][1], zz);
                        z[t] = zz;
                    }

                    unsigned int xw0, xw1, yw0, yw1;
#pragma unroll
                    for (int t = 0; t < 2; t++) {
                        float e[4];
#pragma unroll
                        for (int r = 0; r < 4; r++) {
                            float sv = z[t][r];
                            if (diag) {
                                int key = k0 + t * 16 + quad * 4 + r;
                                int qq  = q0 + s * 16 + l16;
                                sv = (key <= qq) ? sv : -1e30f;
                            }
                            e[r] = __builtin_amdgcn_exp2f(sv);   // raw v_exp_f32
                        }
                        unsigned int w0 = cvt_pk_bf16(e[0], e[1]);
                        unsigned int w1 = cvt_pk_bf16(e[2], e[3]);
                        if (t == 0) { xw0 = w0; xw1 = w1; }
                        else        { yw0 = w0; yw1 = w1; }
                    }

                    // in-register P -> A-frag redistribution (T12), no LDS round-trip
                    u32x2 s32_0 = __builtin_amdgcn_permlane32_swap(xw0, yw0, false, false);
                    u32x2 fin_0 = __builtin_amdgcn_permlane16_swap(s32_0.x, s32_0.y, false, false);
                    u32x2 s32_1 = __builtin_amdgcn_permlane32_swap(xw1, yw1, false, false);
                    u32x2 fin_1 = __builtin_amdgcn_permlane16_swap(s32_1.x, s32_1.y, false, false);
                    union { unsigned int u[4]; bf16x8 v; } pk;
                    pk.u[0] = fin_0.x; pk.u[1] = fin_1.x;
                    pk.u[2] = fin_0.y; pk.u[3] = fin_1.y;
                    bf16x8 pa = pk.v;

#pragma unroll
                    for (int t = 0; t < 4; t++)
                        oacc[s][t] = MFMA16(pa, vb[t], oacc[s][t]);
                    lacc[s] = MFMA16(pa, ones, lacc[s]);  // row-sum via matrix pipe
                }
            }

            // counted drain: c+1's loads done; c+2's (if issued) may stay in flight
            if (more) asm volatile("s_waitcnt vmcnt(2)" ::: "memory");
            else      asm volatile("s_waitcnt vmcnt(0)" ::: "memory");
            __builtin_amdgcn_s_barrier();
            asm volatile("" ::: "memory");
        }
    }

    // normalize + store O as bf16 [B*S, D] at head offset
#pragma unroll
    for (int s = 0; s < 2; s++) {
        float inv[4];
#pragma unroll
        for (int r = 0; r < 4; r++) inv[r] = 1.0f / lacc[s][r];
#pragma unroll
        for (int t = 0; t < 4; t++) {
#pragma unroll
            for (int r = 0; r < 4; r++) {
                float v = oacc[s][t][r] * inv[r];
                O[((size_t)b * SEQ + q0 + s * 16 + quad * 4 + r) * DMODEL
                  + h * HDIM + t * 16 + l16] = f2bf(v);
            }
        }
    }
}

extern "C" void kernel_launch(void* const* d_in, const int* in_sizes, int n_in,
                              void* d_out, int out_size, void* d_ws, size_t ws_size,
                              hipStream_t stream) {
    const float* x      = (const float*)d_in[0];
    const float* w_attn = (const float*)d_in[1];
    const float* w_proj = (const float*)d_in[2];
    float* out = (float*)d_out;

    // workspace (bf16 elems): x | w_attn | w_proj | qkv{Q|K|V^T} | o
    ushort* ws   = (ushort*)d_ws;
    ushort* xb   = ws;
    ushort* wab  = xb  + (size_t)MROWS * DMODEL;
    ushort* wpb  = wab + (size_t)N_QKV * DMODEL;
    ushort* qkvb = wpb + (size_t)DMODEL * DMODEL;
    ushort* ob   = qkvb + (size_t)MROWS * N_QKV;

    ushort* qreg = qkvb;
    ushort* kreg = qkvb + (size_t)MROWS * DMODEL;
    ushort* vtreg = qkvb + 2 * (size_t)MROWS * DMODEL;

    const float qsc = 0.125f * 1.44269504f;  // softmax scale * log2(e) folded into W_q

    // fused casts: x (8192 blk) | w_attn (3072 blk) | w_proj (1024 blk)
    cast3_kernel<<<12288, 256, 0, stream>>>(x, w_attn, w_proj, xb, wab, wpb, qsc);

    // qkv = x @ w_attn^T -> Q | K | V^T regions  (256x128 tiles, 512 thr, phased)
    gemm_bt<2><<<dim3(N_QKV / 128, MROWS / 256), 512, 0, stream>>>(
        (const __hip_bfloat16*)xb, (const __hip_bfloat16*)wab, qreg, nullptr, vtreg,
        MROWS, N_QKV, DMODEL);

    // flash attention -> o (4 pair-waves/block, 4-buffer unroll-4, in-register P)
    attn_kernel<<<1024, 256, 0, stream>>>(qreg, kreg, vtreg, ob);

    // out = o @ w_proj^T   [8192,1024] f32
    gemm_bt<1><<<dim3(DMODEL / 128, MROWS / 256), 512, 0, stream>>>(
        (const __hip_bfloat16*)ob, (const __hip_bfloat16*)wpb, nullptr, out, nullptr,
        MROWS, DMODEL, DMODEL);
}